// Round 5
// baseline (173.168 us; speedup 1.0000x reference)
//
#include <hip/hip_runtime.h>
#include <math.h>

// Problem constants
#define B_   4
#define N_   4096
#define K_   32
#define C_   192
#define CH_  195          // C + 3 (logical GEMM K)
#define KPAD 224          // 7 x 32 ; g_Wp cols: 0..191=channels, 192..194=dp, 195..223=0
#define NKT  7            // K-tiles
#define NNT  4            // N-tiles (64 cols / 16)
#define NPAIR (B_ * N_ / 2)      // 8192 point-pairs
#define GRID  768                // 256 CU x 3 resident blocks (quasi-persistent)

using half8  = __attribute__((ext_vector_type(8))) _Float16;
using half2v = __attribute__((ext_vector_type(2))) _Float16;
using f32x4  = __attribute__((ext_vector_type(4))) float;

// Module-static device scratch
__device__ _Float16 g_Wp[C_ * KPAD];                    // 86016 B (rows pre-scaled by BN inv)
__device__ _Float16 g_xT[(size_t)B_ * N_ * C_];         // 6291456 B

// ---- fused prep: blocks 0..511 transpose x -> g_xT ; blocks 512.. convert W ----
// g_Wp row o, col r: r<192 -> W[o][3+r] (channels), 192..194 -> W[o][r-192] (dp), else 0.
__global__ __launch_bounds__(256) void prep(const float* __restrict__ x,
                                            const float* __restrict__ W,
                                            const float* __restrict__ gamma_,
                                            const float* __restrict__ rvar) {
    const int tid = threadIdx.x;
    if (blockIdx.x < 512) {
        __shared__ float s[32][201];
        const int b  = blockIdx.x >> 7;          // 4 batches x 128 tiles
        const int n0 = (blockIdx.x & 127) * 32;
        const int cl = tid >> 3;                 // 0..31 channel-within-iter
        const int n4 = (tid & 7) * 4;            // 0..28, x4 floats
#pragma unroll
        for (int it = 0; it < 6; ++it) {
            const int c = it * 32 + cl;
            const float4 v = *(const float4*)(x + ((size_t)b * C_ + c) * N_ + n0 + n4);
            s[n4 + 0][c] = v.x; s[n4 + 1][c] = v.y; s[n4 + 2][c] = v.z; s[n4 + 3][c] = v.w;
        }
        __syncthreads();
        const int n  = tid >> 3;                 // 0..31
        const int og = tid & 7;                  // octet-group
#pragma unroll
        for (int it = 0; it < 3; ++it) {
            const int oc = it * 8 + og;          // 0..23 channel octet
            half8 v;
#pragma unroll
            for (int jj = 0; jj < 8; ++jj) v[jj] = (_Float16)s[n][oc * 8 + jj];
            *(half8*)(g_xT + ((size_t)b * N_ + n0 + n) * C_ + oc * 8) = v;
        }
    } else {
        const int i = (blockIdx.x - 512) * 256 + tid;
        if (i < C_ * KPAD) {
            const int o = i / KPAD, r = i - o * KPAD;
            const float inv = gamma_[o] * rsqrtf(rvar[o] + 1e-5f);  // BN scale folded into W
            float v = 0.0f;
            if (r < 192)      v = W[o * CH_ + 3 + r];      // channel weights
            else if (r < 195) v = W[o * CH_ + (r - 192)];  // dp weights
            g_Wp[i] = (_Float16)(v * inv);
        }
    }
}

// ---- main fused kernel (R5): quasi-persistent, W-fragments register-resident ----
// 768 blocks x 256 thr, 3 blocks/CU (reg-bound). Each block owns 10-11 point-pairs
// within one XCD-local half-batch slice. W (86KB) loaded ONCE per block into 84 VGPRs
// -> phase C has zero global loads (was: 21 L2-latency loads per block, 704MB L2 agg).
__global__ __launch_bounds__(256, 3) void la_mfma(
    const float* __restrict__ p,      // [B,N,3]
    const int*   __restrict__ idx,    // [B,N,K]
    const float* __restrict__ gamma_,
    const float* __restrict__ beta_,
    const float* __restrict__ rmean,
    const float* __restrict__ rvar,
    float* __restrict__ out)          // [B,C,N]
{
    __shared__ _Float16 hb[NKT * NNT * 64 * 8];   // 28672 B, B-fragment order
    __shared__ float s_bias[C_], s_fr[32], s_out[C_ * 2];

    const int tid  = threadIdx.x;
    const int lane = tid & 63;
    const int w    = tid >> 6;
    const int l15  = lane & 15;
    const int quad = lane >> 4;

    // XCD-chunked pair assignment: xcd gets pairs [xcd*1024, +1024) -> batch b = xcd>>1
    // (each XCD's gather working set = one half-batch xT slice, 1.57MB, L2-resident).
    const int xcd    = blockIdx.x & 7;
    const int slot   = blockIdx.x >> 3;                    // 0..95
    const int st     = (slot < 64) ? slot * 11 : slot * 10 + 64;
    const int npairs = (slot < 64) ? 11 : 10;              // 64*11 + 32*10 = 1024
    const int pair0  = xcd * 1024 + st;
    const int b      = xcd >> 1;

    if (tid < C_) {
        const float inv = gamma_[tid] * rsqrtf(rvar[tid] + 1e-5f);
        s_bias[tid] = beta_[tid] - rmean[tid] * inv;   // scale part lives in g_Wp
    }
    // s_fr[f] = (50 / 2pi) * 500^(-f/32)   (v_sin takes revolutions)
    if (tid < 32) s_fr[tid] = 7.9577471546f * exp2f(-(float)tid * 0.2801808715263400f);
    __syncthreads();

    float sfr[8];
#pragma unroll
    for (int jj = 0; jj < 8; ++jj) sfr[jj] = s_fr[quad * 8 + jj];

    // ---- W-fragments: load ONCE, resident for whole block (84 VGPRs) ----
    half8 wf[3][NKT];
#pragma unroll
    for (int i = 0; i < 3; ++i)
#pragma unroll
        for (int kt = 0; kt < NKT; ++kt)
            wf[i][kt] = *(const half8*)(g_Wp + (size_t)((w * 3 + i) * 16 + l15) * KPAD
                                              + kt * 32 + quad * 8);

    const int pt = w >> 1;                    // wave-uniform point-within-pair
    const int k  = (w & 1) * 16 + l15;        // neighbor slot 0..31

    // prefetch first gather index
    int j = idx[(size_t)(pair0 * 2 + pt) * K_ + k];

    for (int it = 0; it < npairs; ++it) {
        const int bn0 = (pair0 + it) * 2;
        const int n0  = bn0 & (N_ - 1);
        const int gp  = bn0 + pt;

        const float d0 = p[(size_t)(b * N_ + j) * 3 + 0] - p[(size_t)gp * 3 + 0];
        const float d1 = p[(size_t)(b * N_ + j) * 3 + 1] - p[(size_t)gp * 3 + 1];
        const float d2 = p[(size_t)(b * N_ + j) * 3 + 2] - p[(size_t)gp * 3 + 2];
        const _Float16* xh = g_xT + ((size_t)b * N_ + j) * C_;

        // ---- Phase B: conflict-free frag-order build of h tile ----
#pragma unroll
        for (int i6 = 0; i6 < 6; ++i6) {
            const int chunk = quad + 4 * i6;           // channel octet 0..23
            const half8 v = *(const half8*)(xh + chunk * 8);
            const float dd  = (chunk < 8) ? d0 : ((chunk < 16) ? d1 : d2);
            const float off = (chunk & 4) ? 0.25f : 0.0f;   // cos = sin(+1/4 rev)
            half8 hv;
#pragma unroll
            for (int jj = 0; jj < 8; jj += 2) {
                const float pe0 = __builtin_amdgcn_sinf(fmaf(dd, sfr[jj],     off));
                const float pe1 = __builtin_amdgcn_sinf(fmaf(dd, sfr[jj + 1], off));
                const half2v pe2 = __builtin_bit_cast(half2v, __builtin_amdgcn_cvt_pkrtz(pe0, pe1));
                half2v v2; v2[0] = v[jj]; v2[1] = v[jj + 1];
                const half2v r2 = pe2 * v2 + pe2;   // v_pk_fma_f16: pe*(x+1)
                hv[jj] = r2[0]; hv[jj + 1] = r2[1];
            }
            const int kt = chunk >> 2;              // K-tile 0..5
            *(half8*)(&hb[(size_t)((kt * NNT + w) * 64 + quad * 16 + l15) * 8]) = hv;
        }
        if (quad == 0) {        // octet 24: dp rows 192..194 + zeros (K-tile 6, slot 0)
            half8 hv0 = (half8)(_Float16)0.0f;
            hv0[0] = (_Float16)d0; hv0[1] = (_Float16)d1; hv0[2] = (_Float16)d2;
            *(half8*)(&hb[(size_t)((6 * NNT + w) * 64 + 0 * 16 + l15) * 8]) = hv0;
        } else {                // octets 25..27: zero rows 200..223
            *(half8*)(&hb[(size_t)((6 * NNT + w) * 64 + quad * 16 + l15) * 8]) = (half8)(_Float16)0.0f;
        }
        __syncthreads();

        // prefetch NEXT pair's gather index under the MFMA phase (hides idx L2 latency)
        {
            const int itn = (it + 1 < npairs) ? it + 1 : it;
            j = idx[(size_t)((pair0 + itn) * 2 + pt) * K_ + k];
        }

        // ---- Phase C: transposed MFMA, W operands already in registers ----
        f32x4 acc[3][4];
#pragma unroll
        for (int i = 0; i < 3; ++i)
#pragma unroll
            for (int t = 0; t < 4; ++t) acc[i][t] = (f32x4)0.0f;

#pragma unroll
        for (int kt = 0; kt < NKT; ++kt) {
            half8 bf[4];
#pragma unroll
            for (int t = 0; t < 4; ++t)
                bf[t] = *(const half8*)(&hb[(size_t)((kt * NNT + t) * 64 + lane) * 8]);
#pragma unroll
            for (int i = 0; i < 3; ++i)
#pragma unroll
                for (int t = 0; t < 4; ++t)   // A=h-frag, B=W-frag -> D = (W.h)^T
                    acc[i][t] = __builtin_amdgcn_mfma_f32_16x16x32_f16(bf[t], wf[i][kt], acc[i][t], 0, 0, 0);
        }

        // ---- Epilogue: acc[i][t] = D'[neighbor = t*16+quad*4+r][ch = (w*3+i)*16+l15]
        // 8 in-lane fmax + cross-quad butterfly (xor16, xor32): 16 channels at once.
#pragma unroll
        for (int i = 0; i < 3; ++i) {
            const int m = (w * 3 + i) * 16 + l15;
            float vv[2];
#pragma unroll
            for (int ptc = 0; ptc < 2; ++ptc) {
                const f32x4 va = acc[i][2 * ptc];
                const f32x4 vb = acc[i][2 * ptc + 1];
                float v = fmaxf(fmaxf(fmaxf(va[0], va[1]), fmaxf(va[2], va[3])),
                                fmaxf(fmaxf(vb[0], vb[1]), fmaxf(vb[2], vb[3])));
                v = fmaxf(v, __shfl_xor(v, 16, 64));
                v = fmaxf(v, __shfl_xor(v, 32, 64));
                vv[ptc] = v;
            }
            if (quad == 0) {
                const float bias = s_bias[m];
                float2 o2;
                o2.x = fmaxf(vv[0] + bias, 0.0f);
                o2.y = fmaxf(vv[1] + bias, 0.0f);
                *(float2*)(&s_out[m * 2]) = o2;
            }
        }
        __syncthreads();   // s_out complete; also fences: all waves done reading hb

        // staged store (R2 post-mortem: direct scattered 8B stores broke L2 write-merge).
        // Next iteration's hb-build barrier orders this read before s_out reuse.
        if (tid < C_) {
            const float2 o2 = *(const float2*)(&s_out[tid * 2]);
            *(float2*)(&out[((size_t)b * C_ + tid) * N_ + n0]) = o2;
        }
    }
}

extern "C" void kernel_launch(void* const* d_in, const int* in_sizes, int n_in,
                              void* d_out, int out_size, void* d_ws, size_t ws_size,
                              hipStream_t stream) {
    (void)in_sizes; (void)n_in; (void)out_size; (void)d_ws; (void)ws_size;
    const float* p      = (const float*)d_in[0];
    const float* x      = (const float*)d_in[1];
    const int*   idx    = (const int*)d_in[2];
    const float* W      = (const float*)d_in[3];
    const float* gamma_ = (const float*)d_in[4];
    const float* beta_  = (const float*)d_in[5];
    const float* rmean  = (const float*)d_in[6];
    const float* rvar   = (const float*)d_in[7];
    float* out = (float*)d_out;

    prep<<<512 + (C_ * KPAD + 255) / 256, 256, 0, stream>>>(x, W, gamma_, rvar);
    la_mfma<<<GRID, 256, 0, stream>>>(p, idx, gamma_, beta_, rmean, rvar, out);
}

// Round 6
// 169.253 us; speedup vs baseline: 1.0231x; 1.0231x over previous
//
#include <hip/hip_runtime.h>
#include <math.h>

// Problem constants
#define B_   4
#define N_   4096
#define K_   32
#define C_   192
#define CH_  195          // C + 3 (logical GEMM K)
#define KPAD 224          // 7 x 32 ; g_Wp cols: 0..191=channels, 192..194=dp, 195..223=0
#define NKT  7            // K-tiles
#define NNT  4            // N-tiles (64 cols / 16)
#define GRID 768          // 256 CU x 3 resident blocks (quasi-persistent)

using half8  = __attribute__((ext_vector_type(8))) _Float16;
using half2v = __attribute__((ext_vector_type(2))) _Float16;
using f32x4  = __attribute__((ext_vector_type(4))) float;

// Module-static device scratch
__device__ _Float16 g_Wp[C_ * KPAD];                    // 86016 B (rows pre-scaled by BN inv)
__device__ _Float16 g_xT[(size_t)B_ * N_ * C_];         // 6291456 B

// ---- fused prep: blocks 0..511 transpose x -> g_xT ; blocks 512.. convert W ----
// g_Wp row o, col r: r<192 -> W[o][3+r] (channels), 192..194 -> W[o][r-192] (dp), else 0.
__global__ __launch_bounds__(256) void prep(const float* __restrict__ x,
                                            const float* __restrict__ W,
                                            const float* __restrict__ gamma_,
                                            const float* __restrict__ rvar) {
    const int tid = threadIdx.x;
    if (blockIdx.x < 512) {
        __shared__ float s[32][201];
        const int b  = blockIdx.x >> 7;          // 4 batches x 128 tiles
        const int n0 = (blockIdx.x & 127) * 32;
        const int cl = tid >> 3;                 // 0..31 channel-within-iter
        const int n4 = (tid & 7) * 4;            // 0..28, x4 floats
#pragma unroll
        for (int it = 0; it < 6; ++it) {
            const int c = it * 32 + cl;
            const float4 v = *(const float4*)(x + ((size_t)b * C_ + c) * N_ + n0 + n4);
            s[n4 + 0][c] = v.x; s[n4 + 1][c] = v.y; s[n4 + 2][c] = v.z; s[n4 + 3][c] = v.w;
        }
        __syncthreads();
        const int n  = tid >> 3;                 // 0..31
        const int og = tid & 7;                  // octet-group
#pragma unroll
        for (int it = 0; it < 3; ++it) {
            const int oc = it * 8 + og;          // 0..23 channel octet
            half8 v;
#pragma unroll
            for (int jj = 0; jj < 8; ++jj) v[jj] = (_Float16)s[n][oc * 8 + jj];
            *(half8*)(g_xT + ((size_t)b * N_ + n0 + n) * C_ + oc * 8) = v;
        }
    } else {
        const int i = (blockIdx.x - 512) * 256 + tid;
        if (i < C_ * KPAD) {
            const int o = i / KPAD, r = i - o * KPAD;
            const float inv = gamma_[o] * rsqrtf(rvar[o] + 1e-5f);  // BN scale folded into W
            float v = 0.0f;
            if (r < 192)      v = W[o * CH_ + 3 + r];      // channel weights
            else if (r < 195) v = W[o * CH_ + (r - 192)];  // dp weights
            g_Wp[i] = (_Float16)(v * inv);
        }
    }
}

// ---- main fused kernel (R6): persistent blocks + cross-pair gather prefetch ----
// 768 blocks x 256 thr, 3/CU. W stays in L2 (R4 evidence: FETCH 7.75MB = L2-hot; the
// R5 register-resident-W attempt spilled, FETCH 176MB). Registers instead hold the
// NEXT pair's gather (j, p[j], 6x half8 xT[j]): issued under the current pair's
// sin-chain / MFMA phase, so the idx->p/xT L2 chain leaves the critical path (T14).
__global__ __launch_bounds__(256, 3) void la_mfma(
    const float* __restrict__ p,      // [B,N,3]
    const int*   __restrict__ idx,    // [B,N,K]
    const float* __restrict__ gamma_,
    const float* __restrict__ beta_,
    const float* __restrict__ rmean,
    const float* __restrict__ rvar,
    float* __restrict__ out)          // [B,C,N]
{
    __shared__ _Float16 hb[NKT * NNT * 64 * 8];   // 28672 B, B-fragment order
    __shared__ float s_bias[C_], s_fr[32], s_out[C_ * 2];

    const int tid  = threadIdx.x;
    const int lane = tid & 63;
    const int w    = tid >> 6;
    const int l15  = lane & 15;
    const int quad = lane >> 4;

    // XCD-chunked pair assignment: xcd owns pairs [xcd*1024, +1024) -> b = xcd>>1.
    // Per-XCD gather working set: 2048 xT rows = 786KB + idx 256KB + p 48KB, L2-resident.
    const int xcd    = blockIdx.x & 7;
    const int slot   = blockIdx.x >> 3;                    // 0..95
    const int st     = (slot < 64) ? slot * 11 : slot * 10 + 64;
    const int npairs = (slot < 64) ? 11 : 10;              // 64*11 + 32*10 = 1024
    const int pair0  = xcd * 1024 + st;
    const int b      = xcd >> 1;

    if (tid < C_) {
        const float inv = gamma_[tid] * rsqrtf(rvar[tid] + 1e-5f);
        s_bias[tid] = beta_[tid] - rmean[tid] * inv;   // scale part lives in g_Wp
    }
    // s_fr[f] = (50 / 2pi) * 500^(-f/32)   (v_sin takes revolutions)
    if (tid < 32) s_fr[tid] = 7.9577471546f * exp2f(-(float)tid * 0.2801808715263400f);
    __syncthreads();

    float sfr[8];
#pragma unroll
    for (int jj = 0; jj < 8; ++jj) sfr[jj] = s_fr[quad * 8 + jj];

    const int pt = w >> 1;                    // wave-uniform point-within-pair
    const int k  = (w & 1) * 16 + l15;        // neighbor slot 0..31

    // ---- prologue: full gather for pair 0 into registers ----
    float px0, px1, px2;          // own point coords
    float pj0, pj1, pj2;          // neighbor coords
    half8 xh[6];                  // neighbor features (24 VGPRs)
    {
        const int gp0 = pair0 * 2 + pt;
        const int j0  = idx[(size_t)gp0 * K_ + k];
        px0 = p[(size_t)gp0 * 3 + 0]; px1 = p[(size_t)gp0 * 3 + 1]; px2 = p[(size_t)gp0 * 3 + 2];
        pj0 = p[(size_t)(b * N_ + j0) * 3 + 0];
        pj1 = p[(size_t)(b * N_ + j0) * 3 + 1];
        pj2 = p[(size_t)(b * N_ + j0) * 3 + 2];
        const _Float16* xh0 = g_xT + ((size_t)b * N_ + j0) * C_;
#pragma unroll
        for (int i6 = 0; i6 < 6; ++i6) xh[i6] = *(const half8*)(xh0 + (quad + 4 * i6) * 8);
    }

    for (int it = 0; it < npairs; ++it) {
        const int bn0 = (pair0 + it) * 2;
        const int n0  = bn0 & (N_ - 1);

        // -- independent next-pair loads, issued first (hidden under sin chain) --
        const int itn = (it + 1 < npairs) ? it + 1 : it;
        const int gpn = (pair0 + itn) * 2 + pt;
        const int j_next = idx[(size_t)gpn * K_ + k];
        const float pxn0 = p[(size_t)gpn * 3 + 0];
        const float pxn1 = p[(size_t)gpn * 3 + 1];
        const float pxn2 = p[(size_t)gpn * 3 + 2];

        const float d0 = pj0 - px0, d1 = pj1 - px1, d2 = pj2 - px2;

        // ---- Phase B: conflict-free frag-order build of h tile (operands in regs) ----
#pragma unroll
        for (int i6 = 0; i6 < 6; ++i6) {
            const int chunk = quad + 4 * i6;           // channel octet 0..23
            const half8 v = xh[i6];
            const float dd  = (chunk < 8) ? d0 : ((chunk < 16) ? d1 : d2);
            const float off = (chunk & 4) ? 0.25f : 0.0f;   // cos = sin(+1/4 rev)
            half8 hv;
#pragma unroll
            for (int jj = 0; jj < 8; jj += 2) {
                const float pe0 = __builtin_amdgcn_sinf(fmaf(dd, sfr[jj],     off));
                const float pe1 = __builtin_amdgcn_sinf(fmaf(dd, sfr[jj + 1], off));
                const half2v pe2 = __builtin_bit_cast(half2v, __builtin_amdgcn_cvt_pkrtz(pe0, pe1));
                half2v v2; v2[0] = v[jj]; v2[1] = v[jj + 1];
                const half2v r2 = pe2 * v2 + pe2;   // v_pk_fma_f16: pe*(x+1)
                hv[jj] = r2[0]; hv[jj + 1] = r2[1];
            }
            const int kt = chunk >> 2;              // K-tile 0..5
            *(half8*)(&hb[(size_t)((kt * NNT + w) * 64 + quad * 16 + l15) * 8]) = hv;
        }
        if (quad == 0) {        // octet 24: dp rows 192..194 + zeros (K-tile 6, slot 0)
            half8 hv0 = (half8)(_Float16)0.0f;
            hv0[0] = (_Float16)d0; hv0[1] = (_Float16)d1; hv0[2] = (_Float16)d2;
            *(half8*)(&hb[(size_t)((6 * NNT + w) * 64 + 0 * 16 + l15) * 8]) = hv0;
        } else {                // octets 25..27: zero rows 200..223
            *(half8*)(&hb[(size_t)((6 * NNT + w) * 64 + quad * 16 + l15) * 8]) = (half8)(_Float16)0.0f;
        }
        __syncthreads();

        // -- dependent next-pair loads (j_next arrived during sin chain); these fly
        //    under phase C and are drained by the post-epilogue barrier --
        float pjn0, pjn1, pjn2;
        half8 xhn[6];
        {
            pjn0 = p[(size_t)(b * N_ + j_next) * 3 + 0];
            pjn1 = p[(size_t)(b * N_ + j_next) * 3 + 1];
            pjn2 = p[(size_t)(b * N_ + j_next) * 3 + 2];
            const _Float16* xhp = g_xT + ((size_t)b * N_ + j_next) * C_;
#pragma unroll
            for (int i6 = 0; i6 < 6; ++i6) xhn[i6] = *(const half8*)(xhp + (quad + 4 * i6) * 8);
        }

        // ---- Phase C: transposed MFMA, W streamed from L2 (R4-proven) ----
        f32x4 acc[3][4];
#pragma unroll
        for (int i = 0; i < 3; ++i)
#pragma unroll
            for (int t = 0; t < 4; ++t) acc[i][t] = (f32x4)0.0f;

#pragma unroll
        for (int kt = 0; kt < NKT; ++kt) {
            const int k0 = kt * 32 + quad * 8;
            half8 a[3], bf[4];
#pragma unroll
            for (int i = 0; i < 3; ++i)
                a[i] = *(const half8*)(g_Wp + (size_t)((w * 3 + i) * 16 + l15) * KPAD + k0);
#pragma unroll
            for (int t = 0; t < 4; ++t)
                bf[t] = *(const half8*)(&hb[(size_t)((kt * NNT + t) * 64 + lane) * 8]);
#pragma unroll
            for (int i = 0; i < 3; ++i)
#pragma unroll
                for (int t = 0; t < 4; ++t)   // A=h-frag, B=W-frag -> D = (W.h)^T
                    acc[i][t] = __builtin_amdgcn_mfma_f32_16x16x32_f16(bf[t], a[i], acc[i][t], 0, 0, 0);
        }

        // ---- Epilogue: acc[i][t] = D'[neighbor = t*16+quad*4+r][ch = (w*3+i)*16+l15]
        // 8 in-lane fmax + cross-quad butterfly (xor16, xor32): 16 channels at once.
#pragma unroll
        for (int i = 0; i < 3; ++i) {
            const int m = (w * 3 + i) * 16 + l15;
            float vv[2];
#pragma unroll
            for (int ptc = 0; ptc < 2; ++ptc) {
                const f32x4 va = acc[i][2 * ptc];
                const f32x4 vb = acc[i][2 * ptc + 1];
                float v = fmaxf(fmaxf(fmaxf(va[0], va[1]), fmaxf(va[2], va[3])),
                                fmaxf(fmaxf(vb[0], vb[1]), fmaxf(vb[2], vb[3])));
                v = fmaxf(v, __shfl_xor(v, 16, 64));
                v = fmaxf(v, __shfl_xor(v, 32, 64));
                vv[ptc] = v;
            }
            if (quad == 0) {
                const float bias = s_bias[m];
                float2 o2;
                o2.x = fmaxf(vv[0] + bias, 0.0f);
                o2.y = fmaxf(vv[1] + bias, 0.0f);
                *(float2*)(&s_out[m * 2]) = o2;
            }
        }
        __syncthreads();   // s_out complete; hb reads done; prefetch loads drained

        // staged store (R2 post-mortem: direct scattered 8B stores broke L2 write-merge).
        // Next iteration's post-build barrier orders this read before s_out reuse.
        if (tid < C_) {
            const float2 o2 = *(const float2*)(&s_out[tid * 2]);
            *(float2*)(&out[((size_t)b * C_ + tid) * N_ + n0]) = o2;
        }

        // rotate prefetched gather into current slots
        px0 = pxn0; px1 = pxn1; px2 = pxn2;
        pj0 = pjn0; pj1 = pjn1; pj2 = pjn2;
#pragma unroll
        for (int i6 = 0; i6 < 6; ++i6) xh[i6] = xhn[i6];
    }
}

extern "C" void kernel_launch(void* const* d_in, const int* in_sizes, int n_in,
                              void* d_out, int out_size, void* d_ws, size_t ws_size,
                              hipStream_t stream) {
    (void)in_sizes; (void)n_in; (void)out_size; (void)d_ws; (void)ws_size;
    const float* p      = (const float*)d_in[0];
    const float* x      = (const float*)d_in[1];
    const int*   idx    = (const int*)d_in[2];
    const float* W      = (const float*)d_in[3];
    const float* gamma_ = (const float*)d_in[4];
    const float* beta_  = (const float*)d_in[5];
    const float* rmean  = (const float*)d_in[6];
    const float* rvar   = (const float*)d_in[7];
    float* out = (float*)d_out;

    prep<<<512 + (C_ * KPAD + 255) / 256, 256, 0, stream>>>(x, W, gamma_, rvar);
    la_mfma<<<GRID, 256, 0, stream>>>(p, idx, gamma_, beta_, rmean, rvar, out);
}

// Round 7
// 158.443 us; speedup vs baseline: 1.0929x; 1.0682x over previous
//
#include <hip/hip_runtime.h>
#include <math.h>

// Problem constants
#define B_   4
#define N_   4096
#define K_   32
#define C_   192
#define CH_  195          // C + 3 (logical GEMM K)
#define KPAD 224          // 7 x 32 ; g_Wp cols: 0..191=channels, 192..194=dp, 195..223=0
#define NKT6 6            // K-tiles held in LDS (kt=6 is built in registers)
#define NNT  4            // N-tiles (64 cols / 16)
#define GRID 768          // 256 CU x 3 resident blocks (quasi-persistent)

using half8  = __attribute__((ext_vector_type(8))) _Float16;
using half2v = __attribute__((ext_vector_type(2))) _Float16;
using f32x4  = __attribute__((ext_vector_type(4))) float;

// Module-static device scratch
__device__ _Float16 g_Wp[C_ * KPAD];                    // 86016 B (rows pre-scaled by BN inv)
__device__ _Float16 g_xT[(size_t)B_ * N_ * C_];         // 6291456 B

// ---- fused prep: blocks 0..511 transpose x -> g_xT ; blocks 512.. convert W ----
// g_Wp row o, col r: r<192 -> W[o][3+r] (channels), 192..194 -> W[o][r-192] (dp), else 0.
__global__ __launch_bounds__(256) void prep(const float* __restrict__ x,
                                            const float* __restrict__ W,
                                            const float* __restrict__ gamma_,
                                            const float* __restrict__ rvar) {
    const int tid = threadIdx.x;
    if (blockIdx.x < 512) {
        __shared__ float s[32][201];
        const int b  = blockIdx.x >> 7;          // 4 batches x 128 tiles
        const int n0 = (blockIdx.x & 127) * 32;
        const int cl = tid >> 3;                 // 0..31 channel-within-iter
        const int n4 = (tid & 7) * 4;            // 0..28, x4 floats
#pragma unroll
        for (int it = 0; it < 6; ++it) {
            const int c = it * 32 + cl;
            const float4 v = *(const float4*)(x + ((size_t)b * C_ + c) * N_ + n0 + n4);
            s[n4 + 0][c] = v.x; s[n4 + 1][c] = v.y; s[n4 + 2][c] = v.z; s[n4 + 3][c] = v.w;
        }
        __syncthreads();
        const int n  = tid >> 3;                 // 0..31
        const int og = tid & 7;                  // octet-group
#pragma unroll
        for (int it = 0; it < 3; ++it) {
            const int oc = it * 8 + og;          // 0..23 channel octet
            half8 v;
#pragma unroll
            for (int jj = 0; jj < 8; ++jj) v[jj] = (_Float16)s[n][oc * 8 + jj];
            *(half8*)(g_xT + ((size_t)b * N_ + n0 + n) * C_ + oc * 8) = v;
        }
    } else {
        const int i = (blockIdx.x - 512) * 256 + tid;
        if (i < C_ * KPAD) {
            const int o = i / KPAD, r = i - o * KPAD;
            const float inv = gamma_[o] * rsqrtf(rvar[o] + 1e-5f);  // BN scale folded into W
            float v = 0.0f;
            if (r < 192)      v = W[o * CH_ + 3 + r];      // channel weights
            else if (r < 195) v = W[o * CH_ + (r - 192)];  // dp weights
            g_Wp[i] = (_Float16)(v * inv);
        }
    }
}

// ---- main fused kernel (R7): persistent + hb double-buffer + ONE barrier/pair ----
// 768 blocks x 256 thr, 3/CU (LDS 51.6KB). Per pair: [gather+sin+build buf^c] bar
// [MFMA+epilogue+direct-store]. Build of pair i+1 (into buf^~c) overlaps straggler
// consumers of pair i; rebuild of buf^c at i+2 is ordered by barrier(i+1). Direct
// stores are safe HERE (unlike R2) because consecutive pairs of an output line are
// written by the SAME block on the SAME XCD -> line merges in L2. kt=6 (dp rows)
// is built in registers from s_d, shrinking hb to 6 K-tiles. No register prefetch
// of gather data (R5/R6 post-mortem: any vector live range across the MFMA loop
// spills); only the scalar j index is prefetched.
__global__ __launch_bounds__(256, 3) void la_mfma(
    const float* __restrict__ p,      // [B,N,3]
    const int*   __restrict__ idx,    // [B,N,K]
    const float* __restrict__ gamma_,
    const float* __restrict__ beta_,
    const float* __restrict__ rmean,
    const float* __restrict__ rvar,
    float* __restrict__ out)          // [B,C,N]
{
    __shared__ _Float16 hb[2][NKT6 * NNT * 64 * 8];   // 2 x 24576 B
    __shared__ float s_d[2][3][64];                   // per-col dp (for reg-built kt=6)
    __shared__ float s_bias[C_], s_fr[32];

    const int tid  = threadIdx.x;
    const int lane = tid & 63;
    const int w    = tid >> 6;
    const int l15  = lane & 15;
    const int quad = lane >> 4;

    // XCD-chunked pair assignment: xcd owns pairs [xcd*1024, +1024) -> b = xcd>>1.
    const int xcd    = blockIdx.x & 7;
    const int slot   = blockIdx.x >> 3;                    // 0..95
    const int st     = (slot < 64) ? slot * 11 : slot * 10 + 64;
    const int npairs = (slot < 64) ? 11 : 10;              // 64*11 + 32*10 = 1024
    const int pair0  = xcd * 1024 + st;
    const int b      = xcd >> 1;

    if (tid < C_) {
        const float inv = gamma_[tid] * rsqrtf(rvar[tid] + 1e-5f);
        s_bias[tid] = beta_[tid] - rmean[tid] * inv;   // scale part lives in g_Wp
    }
    // s_fr[f] = (50 / 2pi) * 500^(-f/32)   (v_sin takes revolutions)
    if (tid < 32) s_fr[tid] = 7.9577471546f * exp2f(-(float)tid * 0.2801808715263400f);
    __syncthreads();

    float sfr[8];
#pragma unroll
    for (int jj = 0; jj < 8; ++jj) sfr[jj] = s_fr[quad * 8 + jj];

    const int pt = w >> 1;                    // wave-uniform point-within-pair
    const int k  = (w & 1) * 16 + l15;        // neighbor slot 0..31

    // prefetch first gather index (scalar, 1 VGPR — safe)
    int j = idx[(size_t)(pair0 * 2 + pt) * K_ + k];

    for (int it = 0; it < npairs; ++it) {
        const int cur = it & 1;
        const int bn0 = (pair0 + it) * 2;
        const int n0  = bn0 & (N_ - 1);
        const int gp  = bn0 + pt;

        // ---- Phase B: gather (j known since last iter) + sin + frag-order build ----
        const float d0 = p[(size_t)(b * N_ + j) * 3 + 0] - p[(size_t)gp * 3 + 0];
        const float d1 = p[(size_t)(b * N_ + j) * 3 + 1] - p[(size_t)gp * 3 + 1];
        const float d2 = p[(size_t)(b * N_ + j) * 3 + 2] - p[(size_t)gp * 3 + 2];
        const _Float16* xh = g_xT + ((size_t)b * N_ + j) * C_;

#pragma unroll
        for (int i6 = 0; i6 < 6; ++i6) {
            const int chunk = quad + 4 * i6;           // channel octet 0..23; kt = i6
            const half8 v = *(const half8*)(xh + chunk * 8);
            const float dd  = (chunk < 8) ? d0 : ((chunk < 16) ? d1 : d2);
            const float off = (chunk & 4) ? 0.25f : 0.0f;   // cos = sin(+1/4 rev)
            half8 hv;
#pragma unroll
            for (int jj = 0; jj < 8; jj += 2) {
                const float pe0 = __builtin_amdgcn_sinf(fmaf(dd, sfr[jj],     off));
                const float pe1 = __builtin_amdgcn_sinf(fmaf(dd, sfr[jj + 1], off));
                const half2v pe2 = __builtin_bit_cast(half2v, __builtin_amdgcn_cvt_pkrtz(pe0, pe1));
                half2v v2; v2[0] = v[jj]; v2[1] = v[jj + 1];
                const half2v r2 = pe2 * v2 + pe2;   // v_pk_fma_f16: pe*(x+1)
                hv[jj] = r2[0]; hv[jj + 1] = r2[1];
            }
            *(half8*)(&hb[cur][(size_t)((i6 * NNT + w) * 64 + quad * 16 + l15) * 8]) = hv;
        }
        if (quad == 0) {        // dp for this col -> s_d (kt=6 is built in regs at consume)
            const int col = w * 16 + l15;
            s_d[cur][0][col] = d0; s_d[cur][1][col] = d1; s_d[cur][2][col] = d2;
        }
        __syncthreads();        // the ONLY barrier per pair

        // prefetch next pair's gather index under phase C (hides idx L2 latency)
        {
            const int itn = (it + 1 < npairs) ? it + 1 : it;
            j = idx[(size_t)((pair0 + itn) * 2 + pt) * K_ + k];
        }

        // ---- Phase C: transposed MFMA, W streamed from L2 (R4-proven) ----
        f32x4 acc[3][4];
#pragma unroll
        for (int i = 0; i < 3; ++i)
#pragma unroll
            for (int t = 0; t < 4; ++t) acc[i][t] = (f32x4)0.0f;

#pragma unroll
        for (int kt = 0; kt < NKT6; ++kt) {
            const int k0 = kt * 32 + quad * 8;
            half8 a[3], bf[4];
#pragma unroll
            for (int i = 0; i < 3; ++i)
                a[i] = *(const half8*)(g_Wp + (size_t)((w * 3 + i) * 16 + l15) * KPAD + k0);
#pragma unroll
            for (int t = 0; t < 4; ++t)
                bf[t] = *(const half8*)(&hb[cur][(size_t)((kt * NNT + t) * 64 + lane) * 8]);
#pragma unroll
            for (int i = 0; i < 3; ++i)
#pragma unroll
                for (int t = 0; t < 4; ++t)   // A=h-frag, B=W-frag -> D = (W.h)^T
                    acc[i][t] = __builtin_amdgcn_mfma_f32_16x16x32_f16(bf[t], a[i], acc[i][t], 0, 0, 0);
        }
        // kt = 6: dp rows 192..194. B-frag lane (l15,q'): k=q'*8+e -> only q'==0 rows
        // 192..194 nonzero = [d0,d1,d2,0,...] of col t*16+l15 (from s_d); else zero.
        {
            half8 a6[3];
#pragma unroll
            for (int i = 0; i < 3; ++i)
                a6[i] = *(const half8*)(g_Wp + (size_t)((w * 3 + i) * 16 + l15) * KPAD + 6 * 32 + quad * 8);
#pragma unroll
            for (int t = 0; t < 4; ++t) {
                const int col = t * 16 + l15;
                half8 b6 = (half8)(_Float16)0.0f;
                const float e0 = s_d[cur][0][col];   // quads read same addr -> broadcast
                const float e1 = s_d[cur][1][col];
                const float e2 = s_d[cur][2][col];
                if (quad == 0) {
                    b6[0] = (_Float16)e0; b6[1] = (_Float16)e1; b6[2] = (_Float16)e2;
                }
#pragma unroll
                for (int i = 0; i < 3; ++i)
                    acc[i][t] = __builtin_amdgcn_mfma_f32_16x16x32_f16(b6, a6[i], acc[i][t], 0, 0, 0);
            }
        }

        // ---- Epilogue: acc[i][t] = D'[neighbor = t*16+quad*4+r][ch = (w*3+i)*16+l15]
        // 8 in-lane fmax + cross-quad butterfly (xor16, xor32); direct float2 store
        // (persistent+XCD-chunked: same block revisits the same L2 line -> merges).
#pragma unroll
        for (int i = 0; i < 3; ++i) {
            const int m = (w * 3 + i) * 16 + l15;
            float vv[2];
#pragma unroll
            for (int ptc = 0; ptc < 2; ++ptc) {
                const f32x4 va = acc[i][2 * ptc];
                const f32x4 vb = acc[i][2 * ptc + 1];
                float v = fmaxf(fmaxf(fmaxf(va[0], va[1]), fmaxf(va[2], va[3])),
                                fmaxf(fmaxf(vb[0], vb[1]), fmaxf(vb[2], vb[3])));
                v = fmaxf(v, __shfl_xor(v, 16, 64));
                v = fmaxf(v, __shfl_xor(v, 32, 64));
                vv[ptc] = v;
            }
            if (quad == 0) {
                const float bias = s_bias[m];
                float2 o2;
                o2.x = fmaxf(vv[0] + bias, 0.0f);
                o2.y = fmaxf(vv[1] + bias, 0.0f);
                *(float2*)(&out[((size_t)b * C_ + m) * N_ + n0]) = o2;
            }
        }
        // no trailing barrier: next build writes buf^(~cur); rebuild of buf^cur at
        // it+2 is ordered by barrier(it+1), which all waves reach after consume(it).
    }
}

extern "C" void kernel_launch(void* const* d_in, const int* in_sizes, int n_in,
                              void* d_out, int out_size, void* d_ws, size_t ws_size,
                              hipStream_t stream) {
    (void)in_sizes; (void)n_in; (void)out_size; (void)d_ws; (void)ws_size;
    const float* p      = (const float*)d_in[0];
    const float* x      = (const float*)d_in[1];
    const int*   idx    = (const int*)d_in[2];
    const float* W      = (const float*)d_in[3];
    const float* gamma_ = (const float*)d_in[4];
    const float* beta_  = (const float*)d_in[5];
    const float* rmean  = (const float*)d_in[6];
    const float* rvar   = (const float*)d_in[7];
    float* out = (float*)d_out;

    prep<<<512 + (C_ * KPAD + 255) / 256, 256, 0, stream>>>(x, W, gamma_, rvar);
    la_mfma<<<GRID, 256, 0, stream>>>(p, idx, gamma_, beta_, rmean, rvar, out);
}